// Round 3
// baseline (759.041 us; speedup 1.0000x reference)
//
#include <hip/hip_runtime.h>
#include <cstdint>
#include <cstddef>

#define D 2048
#define L 8
#define KT 4096            // stacked K (pos|neg)
#define BM 256
#define BN 128
#define BK 64
#define NT (KT / BK)       // 64 K-tiles
#define BUFSZ ((BM + BN) * BK)   // f16 elems per LDS buffer

typedef _Float16 f16;
typedef _Float16 f16x2 __attribute__((ext_vector_type(2)));
typedef _Float16 f16x4 __attribute__((ext_vector_type(4)));
typedef _Float16 f16x8 __attribute__((ext_vector_type(8)));
typedef float f32x4 __attribute__((ext_vector_type(4)));

__device__ __forceinline__ void gload16(const void* g, void* l) {
  __builtin_amdgcn_global_load_lds(
      (const __attribute__((address_space(1))) void*)g,
      (__attribute__((address_space(3))) void*)l, 16, 0, 0);
}

// ---- init: A -> Abig = [[A+ | A-] ; [A- | A+]] in f16 ----------------------
__global__ __launch_bounds__(256) void k_init_state(
    const float* __restrict__ A, f16* __restrict__ Ab) {
  size_t i = ((size_t)blockIdx.x * 256 + threadIdx.x) * 8;
  int m = (int)(i >> 11);
  int k = (int)(i & 2047);
  f32x4 a0 = *(const f32x4*)(A + i);
  f32x4 a1 = *(const f32x4*)(A + i + 4);
  f16x8 p, n;
#pragma unroll
  for (int j = 0; j < 4; ++j) {
    p[j]     = (f16)fmaxf(a0[j], 0.f);  n[j]     = (f16)fminf(a0[j], 0.f);
    p[j + 4] = (f16)fmaxf(a1[j], 0.f);  n[j + 4] = (f16)fminf(a1[j], 0.f);
  }
  size_t lo = (size_t)m * KT + k;
  size_t hi = (size_t)(D + m) * KT + k;
  *(f16x8*)(Ab + lo) = p;      *(f16x8*)(Ab + lo + D) = n;
  *(f16x8*)(Ab + hi) = n;      *(f16x8*)(Ab + hi + D) = p;
}

__global__ void k_init_bias(const float* __restrict__ b,
                            float* __restrict__ bl, float* __restrict__ bu) {
  int i = blockIdx.x * 256 + threadIdx.x;
  float v = b[i];
  bl[i] = v; bu[i] = v;
}

// ---- merged per-layer prep: transpose+convert AND bias matvec --------------
// blocks [0,2048):  Bbig[n][koff+k] = (f16)src[k][n]
// blocks [2048,3072): bb[R] += sum_k Ab[R][k]*dbl[k] + Ab[R][k+D]*dbu[k]
__global__ __launch_bounds__(256) void k_prep(
    const float* __restrict__ srcAl, const float* __restrict__ srcAu,
    f16* __restrict__ Bb,
    const f16* __restrict__ Ab, const float* __restrict__ dbl,
    const float* __restrict__ dbu, float* __restrict__ bl,
    float* __restrict__ bu) {
  __shared__ float t[64][65];
  const int bid = blockIdx.x;
  const int tid = threadIdx.x;
  if (bid < 2048) {
    const int z = bid >> 10;
    const int rem = bid & 1023;
    const float* src = z ? srcAu : srcAl;
    const int koff = z ? D : 0;
    const int nb = (rem & 31) * 64;
    const int kb = (rem >> 5) * 64;
    int c = tid & 63, r0 = tid >> 6;
#pragma unroll
    for (int i = 0; i < 64; i += 4)
      t[r0 + i][c] = src[(size_t)(kb + r0 + i) * D + nb + c];
    __syncthreads();
    int cc = (tid & 31) * 2, rr0 = tid >> 5;
#pragma unroll
    for (int i = 0; i < 64; i += 8) {
      int rr = rr0 + i;
      f16x2 h;
      h[0] = (f16)t[cc][rr];
      h[1] = (f16)t[cc + 1][rr];
      *(f16x2*)(Bb + (size_t)(nb + rr) * KT + koff + kb + cc) = h;
    }
  } else {
    const int wave = tid >> 6, lane = tid & 63;
    const int R = (bid - 2048) * 4 + wave;   // 0..4095
    const f16* row = Ab + (size_t)R * KT;
    float acc = 0.f;
    for (int k = lane * 8; k < D; k += 512) {
      f16x8 a = *(const f16x8*)(row + k);
      f16x8 c2 = *(const f16x8*)(row + D + k);
#pragma unroll
      for (int j = 0; j < 8; ++j)
        acc += (float)a[j] * dbl[k + j] + (float)c2[j] * dbu[k + j];
    }
#pragma unroll
    for (int off = 32; off > 0; off >>= 1) acc += __shfl_down(acc, off);
    if (lane == 0) {
      if (R < D) bl[R] += acc; else bu[R - D] += acc;
    }
  }
}

// ---- the step GEMM: C[4096][2048] = Abig @ BbigT^T, sign-split epilogue ----
// 8-phase-style schedule: 2 phases per K-tile, counted vmcnt, setprio.
__global__ __launch_bounds__(512, 2) void k_gemm(
    const f16* __restrict__ A,    // [2D][KT]
    const f16* __restrict__ BT,   // [D][KT]
    f16* __restrict__ An) {       // [2D][KT] next state
  __shared__ __align__(16) f16 lds[3 * BUFSZ];   // 144 KiB tri-buffer

  // bijective XCD swizzle: each XCD owns a 4(y) x 8(x) block region
  const int flat = blockIdx.y * 16 + blockIdx.x;
  const int xcd = flat & 7, idx = flat >> 3;
  const int by = (xcd >> 1) * 4 + (idx >> 3);
  const int bx = (xcd & 1) * 8 + (idx & 7);
  const int m0 = by * BM;
  const int n0 = bx * BN;

  const int tid = threadIdx.x;
  const int wave = tid >> 6, lane = tid & 63;
  const int wm = (wave & 3) * 64, wn = (wave >> 2) * 64;
  const int sub = lane >> 3;                  // row within 8-row region
  const int cg = ((lane & 7) ^ sub) * 8;      // inverse-swizzled src chunk
  const int lr = lane & 15, lq = lane >> 4;

  f32x4 acc[4][4];
#pragma unroll
  for (int m = 0; m < 4; ++m)
#pragma unroll
    for (int n = 0; n < 4; ++n)
      acc[m][n] = (f32x4){0.f, 0.f, 0.f, 0.f};

  // stage one K-tile half: 3 gloads/wave (2 A-regions + 1 B-region)
  auto stage_half = [&](int kt, int buf, int half) {
    f16* bA = lds + buf * BUFSZ;
    f16* bB = bA + BM * BK;
    const size_t gk = (size_t)kt * BK;
#pragma unroll
    for (int i = 0; i < 2; ++i) {
      const int r = (half * 2 + i) * 8 + wave;        // A regions 0..31
      gload16(A + (size_t)(m0 + r * 8 + sub) * KT + gk + cg, bA + r * 512);
    }
    const int rb = half * 8 + wave;                   // B regions 0..15
    gload16(BT + (size_t)(n0 + rb * 8 + sub) * KT + gk + cg, bB + rb * 512);
  };

  // prologue: 2 tiles in flight, wait for the first
  stage_half(0, 0, 0); stage_half(0, 0, 1);
  stage_half(1, 1, 0); stage_half(1, 1, 1);
  asm volatile("s_waitcnt vmcnt(6)" ::: "memory");
  __builtin_amdgcn_sched_barrier(0);
  __builtin_amdgcn_s_barrier();

  for (int t = 0; t < NT; ++t) {
    const f16* bA = lds + (t % 3) * BUFSZ;
    const f16* bB = bA + BM * BK;
    const int sbuf = (t + 2) % 3;
    const bool pf = (t + 2 < NT);
#pragma unroll
    for (int s = 0; s < 2; ++s) {
      // phase: issue ds_reads for this k-half + 3 prefetch loads
      const int ch = ((s * 4 + lq) ^ (lane & 7)) * 8;  // swizzled read chunk
      f16x8 af[4], bf[4];
#pragma unroll
      for (int m = 0; m < 4; ++m)
        af[m] = *(const f16x8*)(bA + (wm + m * 16 + lr) * BK + ch);
#pragma unroll
      for (int n = 0; n < 4; ++n)
        bf[n] = *(const f16x8*)(bB + (wn + n * 16 + lr) * BK + ch);
      if (pf) stage_half(t + 2, sbuf, s);
      if (s == 1 && t + 1 < NT) {
        // counted wait: next tile's loads landed; keep t+2's 6 in flight
        if (pf) asm volatile("s_waitcnt vmcnt(6)" ::: "memory");
        else    asm volatile("s_waitcnt vmcnt(0)" ::: "memory");
      }
      __builtin_amdgcn_sched_barrier(0);
      __builtin_amdgcn_s_barrier();
      asm volatile("s_waitcnt lgkmcnt(0)" ::: "memory");
      __builtin_amdgcn_sched_barrier(0);
      __builtin_amdgcn_s_setprio(1);
#pragma unroll
      for (int m = 0; m < 4; ++m)
#pragma unroll
        for (int n = 0; n < 4; ++n)
          acc[m][n] = __builtin_amdgcn_mfma_f32_16x16x32_f16(
              bf[n], af[m], acc[m][n], 0, 0, 0);
      __builtin_amdgcn_s_setprio(0);
      __builtin_amdgcn_sched_barrier(0);
      __builtin_amdgcn_s_barrier();
    }
  }

  const int low = (m0 < D) ? 1 : 0;   // block-uniform: lower vs upper chain
#pragma unroll
  for (int m = 0; m < 4; ++m) {
#pragma unroll
    for (int n = 0; n < 4; ++n) {
      const size_t row = (size_t)(m0 + wm + m * 16 + lr);
      const int col = n0 + wn + n * 16 + lq * 4;
      f16x4 p, q;
#pragma unroll
      for (int r = 0; r < 4; ++r) {
        float v = acc[m][n][r];
        p[r] = (f16)fmaxf(v, 0.f);
        q[r] = (f16)fminf(v, 0.f);
      }
      f16* base = An + row * KT + col;
      if (low) { *(f16x4*)base = p; *(f16x4*)(base + D) = q; }
      else     { *(f16x4*)base = q; *(f16x4*)(base + D) = p; }
    }
  }
}

// ---- final: out[R] = sum_k Ab[R][k]*lo[k] + Ab[R][k+D]*up[k] + bias --------
__global__ __launch_bounds__(256) void k_final(
    const f16* __restrict__ Ab, const float* __restrict__ lo,
    const float* __restrict__ up, const float* __restrict__ bl,
    const float* __restrict__ bu, float* __restrict__ out) {
  const int wave = threadIdx.x >> 6, lane = threadIdx.x & 63;
  const int R = blockIdx.x * 4 + wave;    // 0..4095
  const f16* row = Ab + (size_t)R * KT;
  float acc = 0.f;
  for (int k = lane * 8; k < D; k += 512) {
    f16x8 a = *(const f16x8*)(row + k);
    f16x8 c = *(const f16x8*)(row + D + k);
#pragma unroll
    for (int j = 0; j < 8; ++j)
      acc += (float)a[j] * lo[k + j] + (float)c[j] * up[k + j];
  }
#pragma unroll
  for (int off = 32; off > 0; off >>= 1) acc += __shfl_down(acc, off);
  if (lane == 0)
    out[R] = acc + (R < D ? bl[R] : bu[R - D]);
}

// ---- host ------------------------------------------------------------------
extern "C" void kernel_launch(void* const* d_in, const int* in_sizes, int n_in,
                              void* d_out, int out_size, void* d_ws, size_t ws_size,
                              hipStream_t stream) {
  (void)in_sizes; (void)n_in; (void)out_size; (void)ws_size;
  const float* A   = (const float*)d_in[0];
  const float* b   = (const float*)d_in[1];
  const float* hAl = (const float*)d_in[2];
  const float* hAu = (const float*)d_in[3];
  const float* hbl = (const float*)d_in[4];
  const float* hbu = (const float*)d_in[5];
  const float* lo  = (const float*)d_in[6];
  const float* up  = (const float*)d_in[7];
  float* out = (float*)d_out;

  const size_t AS = (size_t)2 * D * KT;     // Abig elems (f16)
  const size_t MS = (size_t)D * D;
  f16* Ab0 = (f16*)d_ws;
  f16* Ab1 = Ab0 + AS;
  f16* Bb  = Ab1 + AS;                      // [D][KT]
  float* bl = (float*)(Bb + (size_t)D * KT);
  float* bu = bl + D;

  k_init_state<<<dim3((unsigned)(MS / (256 * 8))), 256, 0, stream>>>(A, Ab0);
  k_init_bias<<<dim3(D / 256), 256, 0, stream>>>(b, bl, bu);

  f16* cur = Ab0;
  f16* nxt = Ab1;
  for (int t = 0; t < L; ++t) {
    const int layer = L - 1 - t;
    k_prep<<<dim3(2048 + 1024), 256, 0, stream>>>(
        hAl + (size_t)layer * MS, hAu + (size_t)layer * MS, Bb,
        cur, hbl + (size_t)layer * D, hbu + (size_t)layer * D, bl, bu);
    k_gemm<<<dim3(D / BN, 2 * D / BM), 512, 0, stream>>>(cur, Bb, nxt);
    f16* tmp = cur; cur = nxt; nxt = tmp;
  }
  k_final<<<dim3(2 * D / 4), 256, 0, stream>>>(cur, lo, up, bl, bu, out);
}

// Round 4
// 695.015 us; speedup vs baseline: 1.0921x; 1.0921x over previous
//
#include <hip/hip_runtime.h>
#include <cstdint>
#include <cstddef>

#define D 2048
#define L 8
#define KT 4096            // stacked K (pos|neg)
#define BM 256
#define BN 128
#define BK 64
#define NT (KT / BK)       // 64 K-tiles
#define BUFSZ ((BM + BN) * BK)   // f16 elems per LDS buffer

typedef _Float16 f16;
typedef _Float16 f16x4 __attribute__((ext_vector_type(4)));
typedef _Float16 f16x8 __attribute__((ext_vector_type(8)));
typedef float f32x4 __attribute__((ext_vector_type(4)));

__device__ __forceinline__ void gload16(const void* g, void* l) {
  __builtin_amdgcn_global_load_lds(
      (const __attribute__((address_space(1))) void*)g,
      (__attribute__((address_space(3))) void*)l, 16, 0, 0);
}

// ---- init: A -> Abig = [[A+|A-];[A-|A+]], bias init + step-0 contribution --
// one block per row m; also zeroes outacc (blocks 0,1)
__global__ __launch_bounds__(256) void k_init(
    const float* __restrict__ A, const float* __restrict__ b,
    const float* __restrict__ db1, const float* __restrict__ db2,  // layer 7
    f16* __restrict__ Ab, float* __restrict__ blbu, float* __restrict__ outacc) {
  const int m = blockIdx.x, tid = threadIdx.x;
  if (m < 2) {
    f32x4 z = {0.f, 0.f, 0.f, 0.f};
    *(f32x4*)(outacc + m * 2048 + tid * 8) = z;
    *(f32x4*)(outacc + m * 2048 + tid * 8 + 4) = z;
  }
  const int k = tid * 8;
  size_t i = (size_t)m * D + k;
  f32x4 a0 = *(const f32x4*)(A + i);
  f32x4 a1 = *(const f32x4*)(A + i + 4);
  f16x8 p, n;
  float cL = 0.f, cU = 0.f;
#pragma unroll
  for (int j = 0; j < 8; ++j) {
    float v = (j < 4) ? a0[j] : a1[j - 4];
    float pf = fmaxf(v, 0.f), nf = fminf(v, 0.f);
    p[j] = (f16)pf; n[j] = (f16)nf;
    float w1 = db1[k + j], w2 = db2[k + j];
    cL += pf * w1 + nf * w2;
    cU += pf * w2 + nf * w1;
  }
  size_t lo = (size_t)m * KT + k;
  size_t hi = (size_t)(D + m) * KT + k;
  *(f16x8*)(Ab + lo) = p;      *(f16x8*)(Ab + lo + D) = n;
  *(f16x8*)(Ab + hi) = n;      *(f16x8*)(Ab + hi + D) = p;

  __shared__ float redL[4], redU[4];
#pragma unroll
  for (int off = 32; off > 0; off >>= 1) {
    cL += __shfl_down(cL, off);
    cU += __shfl_down(cU, off);
  }
  const int wave = tid >> 6, lane = tid & 63;
  if (lane == 0) { redL[wave] = cL; redU[wave] = cU; }
  __syncthreads();
  if (tid == 0) {
    float bL = b[m] + redL[0] + redL[1] + redL[2] + redL[3];
    float bU = b[m] + redU[0] + redU[1] + redU[2] + redU[3];
    blbu[m] = bL; blbu[D + m] = bU;
  }
}

// ---- LDS-free transpose panel: Bb[n][koff+k] = (f16)src[k][n] --------------
// blk512 in [0,1024): 512 blocks per matrix; block covers 64 cols x 128 k
__device__ __forceinline__ void transpose_panel(
    const float* __restrict__ srcAl, const float* __restrict__ srcAu,
    f16* __restrict__ Bb, int blk512, int tid) {
  const int z = blk512 >> 9;
  const int rem = blk512 & 511;
  const float* src = z ? srcAu : srcAl;
  const int koff = z ? D : 0;
  const int nb = (rem & 31) * 64;
  const int kb = (rem >> 5) * 128;
  const int lane = tid & 63, w = tid >> 6;
  const int col = nb + lane;
  const int k0 = kb + w * 16;
  float v[16];
#pragma unroll
  for (int j = 0; j < 16; ++j)
    v[j] = src[(size_t)(k0 + j) * D + col];
  f16x8 h0, h1;
#pragma unroll
  for (int j = 0; j < 8; ++j) { h0[j] = (f16)v[j]; h1[j] = (f16)v[8 + j]; }
  f16* dst = Bb + (size_t)col * KT + koff + k0;
  *(f16x8*)dst = h0;
  *(f16x8*)(dst + 8) = h1;
}

__global__ __launch_bounds__(512) void k_prep(
    const float* __restrict__ srcAl, const float* __restrict__ srcAu,
    f16* __restrict__ Bb) {
  transpose_panel(srcAl, srcAu, Bb, blockIdx.x, threadIdx.x);
}

// ---- step GEMM + fused bias-epilogue + backfill transpose ------------------
__global__ __launch_bounds__(512, 2) void k_gemm(
    const f16* __restrict__ A,     // [2D][KT] state
    const f16* __restrict__ BT,    // [D][KT] current layer (transposed)
    f16* __restrict__ BTn,         // next layer's B buffer (backfill target)
    const float* __restrict__ nAl, const float* __restrict__ nAu,  // next layer src
    const float* __restrict__ w1, const float* __restrict__ w2,    // bias weights
    float* __restrict__ bdst,      // blbu (t<7) or outacc (t=7)
    f16* __restrict__ An) {        // [2D][KT] next state
  __shared__ __align__(16) f16 lds[3 * BUFSZ];   // 144 KiB tri-buffer

  if (blockIdx.x >= 256) {   // backfill: transpose next layer
    transpose_panel(nAl, nAu, BTn, blockIdx.x - 256, threadIdx.x);
    return;
  }

  // bijective XCD swizzle over the 16x16 tile grid
  const int flat = blockIdx.x;
  const int xcd = flat & 7, idx = flat >> 3;
  const int by = (xcd >> 1) * 4 + (idx >> 3);
  const int bx = (xcd & 1) * 8 + (idx & 7);
  const int m0 = by * BM;
  const int n0 = bx * BN;

  const int tid = threadIdx.x;
  const int wave = tid >> 6, lane = tid & 63;
  const int wm = (wave & 3) * 64, wn = (wave >> 2) * 64;
  const int sub = lane >> 3;                  // row within 8-row region
  const int cg = ((lane & 7) ^ sub) * 8;      // inverse-swizzled src chunk
  const int lr = lane & 15, lq = lane >> 4;

  f32x4 acc[4][4];
#pragma unroll
  for (int m = 0; m < 4; ++m)
#pragma unroll
    for (int n = 0; n < 4; ++n)
      acc[m][n] = (f32x4){0.f, 0.f, 0.f, 0.f};

  auto stage = [&](int kt, int buf) {
    f16* bA = lds + buf * BUFSZ;
    f16* bB = bA + BM * BK;
    const size_t gk = (size_t)kt * BK;
#pragma unroll
    for (int i = 0; i < 4; ++i) {
      const int r = i * 8 + wave;             // 32 regions x 8 rows (A)
      gload16(A + (size_t)(m0 + r * 8 + sub) * KT + gk + cg, bA + r * 512);
    }
#pragma unroll
    for (int i = 0; i < 2; ++i) {
      const int r = i * 8 + wave;             // 16 regions x 8 rows (B)
      gload16(BT + (size_t)(n0 + r * 8 + sub) * KT + gk + cg, bB + r * 512);
    }
  };

  // prologue: 2 tiles in flight, wait for the first
  stage(0, 0);
  stage(1, 1);
  asm volatile("s_waitcnt vmcnt(6)" ::: "memory");
  __builtin_amdgcn_sched_barrier(0);
  __builtin_amdgcn_s_barrier();
  __builtin_amdgcn_sched_barrier(0);

  for (int t = 0; t < NT; ++t) {
    const f16* bA = lds + (t % 3) * BUFSZ;
    const f16* bB = bA + BM * BK;
    if (t + 2 < NT) stage(t + 2, (t + 2) % 3);   // prefetch 2 tiles ahead
#pragma unroll
    for (int s = 0; s < 2; ++s) {
      const int ch = ((s * 4 + lq) ^ (lane & 7)) * 8;  // swizzled read chunk
      f16x8 af[4], bf[4];
#pragma unroll
      for (int m = 0; m < 4; ++m)
        af[m] = *(const f16x8*)(bA + (wm + m * 16 + lr) * BK + ch);
#pragma unroll
      for (int n = 0; n < 4; ++n)
        bf[n] = *(const f16x8*)(bB + (wn + n * 16 + lr) * BK + ch);
      __builtin_amdgcn_s_setprio(1);
#pragma unroll
      for (int m = 0; m < 4; ++m)
#pragma unroll
        for (int n = 0; n < 4; ++n)
          acc[m][n] = __builtin_amdgcn_mfma_f32_16x16x32_f16(
              bf[n], af[m], acc[m][n], 0, 0, 0);
      __builtin_amdgcn_s_setprio(0);
    }
    if (t + 2 < NT) {
      asm volatile("s_waitcnt vmcnt(6)" ::: "memory");
    } else if (t + 1 < NT) {
      asm volatile("s_waitcnt vmcnt(0)" ::: "memory");
    }
    __builtin_amdgcn_sched_barrier(0);
    __builtin_amdgcn_s_barrier();
    __builtin_amdgcn_sched_barrier(0);
  }

  // ---- epilogue: sign-split store + fused bias contribution ----
  const int low = (m0 < D) ? 1 : 0;
  f32x4 w1v[4], w2v[4];
#pragma unroll
  for (int n = 0; n < 4; ++n) {
    const int col = n0 + wn + n * 16 + lq * 4;
    w1v[n] = *(const f32x4*)(w1 + col);
    w2v[n] = *(const f32x4*)(w2 + col);
  }
  float rowsum[4] = {0.f, 0.f, 0.f, 0.f};
#pragma unroll
  for (int m = 0; m < 4; ++m) {
#pragma unroll
    for (int n = 0; n < 4; ++n) {
      const size_t row = (size_t)(m0 + wm + m * 16 + lr);
      const int col = n0 + wn + n * 16 + lq * 4;
      f16x4 p, q;
#pragma unroll
      for (int r = 0; r < 4; ++r) {
        float v = acc[m][n][r];
        float pf = fmaxf(v, 0.f), qf = fminf(v, 0.f);
        p[r] = (f16)pf;
        q[r] = (f16)qf;
        float wa = low ? w1v[n][r] : w2v[n][r];
        float wb = low ? w2v[n][r] : w1v[n][r];
        rowsum[m] += pf * wa + qf * wb;
      }
      f16* base = An + row * KT + col;
      if (low) { *(f16x4*)base = p; *(f16x4*)(base + D) = q; }
      else     { *(f16x4*)base = q; *(f16x4*)(base + D) = p; }
    }
  }
#pragma unroll
  for (int m = 0; m < 4; ++m) {
    float v = rowsum[m];
    v += __shfl_down(v, 32);
    v += __shfl_down(v, 16);
    if (lane < 16)
      atomicAdd(bdst + m0 + wm + m * 16 + lane, v);
  }
}

// ---- final: out[R] = outacc[R] + blbu[R] -----------------------------------
__global__ __launch_bounds__(256) void k_final(
    const float* __restrict__ outacc, const float* __restrict__ blbu,
    float* __restrict__ out) {
  const int R = blockIdx.x * 256 + threadIdx.x;
  out[R] = outacc[R] + blbu[R];
}

// ---- host ------------------------------------------------------------------
extern "C" void kernel_launch(void* const* d_in, const int* in_sizes, int n_in,
                              void* d_out, int out_size, void* d_ws, size_t ws_size,
                              hipStream_t stream) {
  (void)in_sizes; (void)n_in; (void)out_size;
  const float* A   = (const float*)d_in[0];
  const float* b   = (const float*)d_in[1];
  const float* hAl = (const float*)d_in[2];
  const float* hAu = (const float*)d_in[3];
  const float* hbl = (const float*)d_in[4];
  const float* hbu = (const float*)d_in[5];
  const float* lo  = (const float*)d_in[6];
  const float* up  = (const float*)d_in[7];
  float* out = (float*)d_out;

  const size_t AS = (size_t)2 * D * KT;     // Abig elems (f16)
  const size_t BS = (size_t)D * KT;         // Bb elems (f16)
  const size_t MS = (size_t)D * D;
  char* base = (char*)d_ws;
  f16* Ab0   = (f16*)base;
  f16* Ab1   = Ab0 + AS;
  f16* Bb0   = Ab1 + AS;
  float* blbu   = (float*)(Bb0 + BS);
  float* outacc = blbu + 2 * D;
  f16* Bb1   = (f16*)(outacc + 2 * D);
  const size_t need_fused = (size_t)((char*)(Bb1 + BS) - base);
  const bool fused = ws_size >= need_fused;

  k_init<<<dim3(D), 256, 0, stream>>>(
      A, b, hbl + (size_t)7 * D, hbu + (size_t)7 * D, Ab0, blbu, outacc);
  k_prep<<<dim3(1024), 512, 0, stream>>>(          // layer 7 -> Bb0
      hAl + (size_t)7 * MS, hAu + (size_t)7 * MS, Bb0);

  f16* cur = Ab0;
  f16* nxt = Ab1;
  for (int t = 0; t < L; ++t) {
    const int nlayer = 6 - t;   // layer for step t+1 (bias weights + transpose)
    const float* w1 = (t < 7) ? hbl + (size_t)nlayer * D : lo;
    const float* w2 = (t < 7) ? hbu + (size_t)nlayer * D : up;
    float* bd = (t < 7) ? blbu : outacc;
    f16* BT  = (fused && (t & 1)) ? Bb1 : Bb0;
    f16* BTn = fused ? ((t & 1) ? Bb0 : Bb1) : Bb0;
    const float* nl = (t < 7) ? hAl + (size_t)nlayer * MS : hAl;
    const float* nu = (t < 7) ? hAu + (size_t)nlayer * MS : hAu;
    if (!fused && t > 0)
      k_prep<<<dim3(1024), 512, 0, stream>>>(
          hAl + (size_t)(7 - t) * MS, hAu + (size_t)(7 - t) * MS, Bb0);
    const unsigned grid = (fused && t < 7) ? 1280u : 256u;
    k_gemm<<<dim3(grid), 512, 0, stream>>>(cur, BT, BTn, nl, nu, w1, w2, bd, nxt);
    f16* tmp = cur; cur = nxt; nxt = tmp;
  }
  k_final<<<dim3(2 * D / 256), 256, 0, stream>>>(outacc, blbu, out);
}